// Round 18
// baseline (180.146 us; speedup 1.0000x reference)
//
#include <hip/hip_runtime.h>
#include <stdint.h>

typedef __bf16 bf16x8 __attribute__((ext_vector_type(8)));
typedef float  f32x4  __attribute__((ext_vector_type(4)));

#define HH 384
#define WW 384
#define NPIX (HH*WW)
#define NC 3
#define NPATCH 576
#define EMB 768
#define PLEN 768
#define KSTEPS 24
#define NLOC (64*576)            /* 36864 */
#define W1_UNITS (32*KSTEPS*64)  /* 49152 16B-units */
#define W2_UNITS (48*KSTEPS*64)  /* 73728 16B-units */
#define W2_OFF   (W1_UNITS*8)                 /* u16 units */
#define AP_OFF   ((W1_UNITS+W2_UNITS)*8)      /* u16 units */
#define SA_OFF   (AP_OFF + NLOC*PLEN)         /* u16 units */
#define P0_WBLKS ((W1_UNITS+W2_UNITS)/256)    /* 480 */
#define P0_BANDS (64*24)                      /* 1536 */

__device__ __forceinline__ uint16_t f2bf(float f) {
    uint32_t u = __builtin_bit_cast(uint32_t, f);
    u += 0x7FFFu + ((u >> 16) & 1u);
    return (uint16_t)(u >> 16);
}
__device__ __forceinline__ uint32_t pk2(float a, float b) {
    return (uint32_t)f2bf(a) | ((uint32_t)f2bf(b) << 16);
}
__device__ __forceinline__ float bf2f(uint16_t u) {
    return __builtin_bit_cast(float, (uint32_t)u << 16);
}
__device__ __forceinline__ float bits_f(uint32_t u) {
    return __builtin_bit_cast(float, u);
}

// ===== P0 ==================================================================
// Weights -> MFMA-fragment bf16. W1 uses the PERMUTED k-order (k = q*3+c,
// matching the interleaved Ap): src elem = (k%3)*256 + k/3. W2 stays planar.
// Band blocks: im2col with channel-interleaved rows: Ap[patch][q*3+c].
__global__ __launch_bounds__(256)
void p0_prepass(const float* __restrict__ offw, const float* __restrict__ projw,
                const float* __restrict__ pix, uint16_t* __restrict__ wz) {
    __shared__ uint16_t L[3 * 16 * 384];   // planar band cache (bf16)
    int b = blockIdx.x;
    if (b < P0_WBLKS) {
        int u = b * 256 + threadIdx.x;
        int lane = u & 63;
        if (u < W1_UNITS) {
            int t  = u >> 6;
            int ks = t % KSTEPS;
            int nt = t / KSTEPS;
            int n  = nt * 16 + (lane & 15);
            int k0 = ks * 32 + (lane >> 4) * 8;
            const float* src = offw + (size_t)n * PLEN;
            uint16_t tmp[8];
            #pragma unroll
            for (int e = 0; e < 8; ++e) {
                int k = k0 + e;
                int q = k / 3, c = k - q * 3;
                tmp[e] = f2bf(src[c * 256 + q]);
            }
            uint4 w;
            w.x = tmp[0] | ((uint32_t)tmp[1] << 16);
            w.y = tmp[2] | ((uint32_t)tmp[3] << 16);
            w.z = tmp[4] | ((uint32_t)tmp[5] << 16);
            w.w = tmp[6] | ((uint32_t)tmp[7] << 16);
            *(uint4*)(wz + (size_t)u * 8) = w;
        } else {
            int uu = u - W1_UNITS;
            int t2 = uu >> 6;
            int ks = t2 % KSTEPS;
            int nt = t2 / KSTEPS;
            int n  = nt * 16 + (lane & 15);
            int k0 = ks * 32 + (lane >> 4) * 8;
            const float4* s4 = (const float4*)(projw + (size_t)n * PLEN + k0);
            float4 v0 = s4[0], v1 = s4[1];
            uint4 w;
            w.x = pk2(v0.x, v0.y); w.y = pk2(v0.z, v0.w);
            w.z = pk2(v1.x, v1.y); w.w = pk2(v1.z, v1.w);
            *(uint4*)(wz + (size_t)u * 8) = w;
        }
        return;
    }
    int band = b - P0_WBLKS;               // 0..1535
    int img  = band / 24;
    int yb   = band - img * 24;            // ho
    const float* src = pix + (size_t)img * NC * NPIX + (size_t)yb * 16 * WW;
    #pragma unroll
    for (int i = 0; i < 18; ++i) {
        int u = threadIdx.x + i * 256;     // 0..4607 float4 groups
        int c = u / 1536;
        int r = u - c * 1536;
        float4 v = *(const float4*)(src + (size_t)c * NPIX + (size_t)r * 4);
        uint2 o;
        o.x = pk2(v.x, v.y);
        o.y = pk2(v.z, v.w);
        *(uint2*)&L[c * 6144 + r * 4] = o;
    }
    __syncthreads();
    // emit 24 patch rows, interleaved k = q*3+c, contiguous 1536B each
    uint16_t* ap = wz + AP_OFF + (size_t)(img * NPATCH + yb * 24) * PLEN;
    #pragma unroll
    for (int i = 0; i < 9; ++i) {
        int u  = threadIdx.x + i * 256;    // 0..2303 chunks of 8
        int p  = u / 96;
        int k8 = (u - p * 96) * 8;
        uint16_t tmp[8];
        #pragma unroll
        for (int e = 0; e < 8; ++e) {
            int k = k8 + e;
            int q = k / 3, c = k - q * 3;
            int ii = q >> 4, j = q & 15;
            tmp[e] = L[(c * 16 + ii) * 384 + p * 16 + j];
        }
        uint4 d;
        d.x = tmp[0] | ((uint32_t)tmp[1] << 16);
        d.y = tmp[2] | ((uint32_t)tmp[3] << 16);
        d.z = tmp[4] | ((uint32_t)tmp[5] << 16);
        d.w = tmp[6] | ((uint32_t)tmp[7] << 16);
        *(uint4*)(ap + (size_t)p * PLEN + k8) = d;
    }
}

// GEMM macro body: one K-iteration (2 K-steps) reading Asb[BUF], consuming
// B sets (be, bo). Shared by K1/K3.
#define GEMM_ITER(BUF, be, bo)                                                  \
    {                                                                           \
        const int u0 = (lg ^ (lr & 7)) * 8;                                     \
        bf16x8 a0 = *(const bf16x8*)&Asb[BUF][wm * 64 +  0 + lr][u0];           \
        bf16x8 a1 = *(const bf16x8*)&Asb[BUF][wm * 64 + 16 + lr][u0];           \
        bf16x8 a2 = *(const bf16x8*)&Asb[BUF][wm * 64 + 32 + lr][u0];           \
        bf16x8 a3 = *(const bf16x8*)&Asb[BUF][wm * 64 + 48 + lr][u0];           \
        _Pragma("unroll")                                                       \
        for (int nt = 0; nt < 4; ++nt) {                                        \
            acc[0][nt] = __builtin_amdgcn_mfma_f32_16x16x32_bf16(a0, be[nt], acc[0][nt], 0, 0, 0); \
            acc[1][nt] = __builtin_amdgcn_mfma_f32_16x16x32_bf16(a1, be[nt], acc[1][nt], 0, 0, 0); \
            acc[2][nt] = __builtin_amdgcn_mfma_f32_16x16x32_bf16(a2, be[nt], acc[2][nt], 0, 0, 0); \
            acc[3][nt] = __builtin_amdgcn_mfma_f32_16x16x32_bf16(a3, be[nt], acc[3][nt], 0, 0, 0); \
        }                                                                       \
        const int u1 = ((4 + lg) ^ (lr & 7)) * 8;                               \
        bf16x8 c0 = *(const bf16x8*)&Asb[BUF][wm * 64 +  0 + lr][u1];           \
        bf16x8 c1 = *(const bf16x8*)&Asb[BUF][wm * 64 + 16 + lr][u1];           \
        bf16x8 c2 = *(const bf16x8*)&Asb[BUF][wm * 64 + 32 + lr][u1];           \
        bf16x8 c3 = *(const bf16x8*)&Asb[BUF][wm * 64 + 48 + lr][u1];           \
        _Pragma("unroll")                                                       \
        for (int nt = 0; nt < 4; ++nt) {                                        \
            acc[0][nt] = __builtin_amdgcn_mfma_f32_16x16x32_bf16(c0, bo[nt], acc[0][nt], 0, 0, 0); \
            acc[1][nt] = __builtin_amdgcn_mfma_f32_16x16x32_bf16(c1, bo[nt], acc[1][nt], 0, 0, 0); \
            acc[2][nt] = __builtin_amdgcn_mfma_f32_16x16x32_bf16(c2, bo[nt], acc[2][nt], 0, 0, 0); \
            acc[3][nt] = __builtin_amdgcn_mfma_f32_16x16x32_bf16(c3, bo[nt], acc[3][nt], 0, 0, 0); \
        }                                                                       \
    }

// ===== K1: GEMM1 (offset conv) — deep B-prefetch (full-iteration ahead) ====
__global__ __launch_bounds__(256, 3)
void k1_offgemm(const uint16_t* __restrict__ wz, const float* __restrict__ offb,
                uint16_t* __restrict__ sa) {
    __shared__ __align__(16) uint16_t Asb[2][128][64];   // 32 KB dbuf
    const int tid = threadIdx.x, wv = tid >> 6, lane = tid & 63;
    const int lr = lane & 15, lg = lane >> 4;
    const int wm = wv >> 1, wn = wv & 1;
    int bid = (int)blockIdx.x;                 // 1152 = 8 x 144
    const int fin   = (bid & 7) * 144 + (bid >> 3);
    const int mtile = fin >> 2;
    const int nc    = fin & 3;
    const int loc0  = mtile * 128;
    const int n0    = nc * 128;
    const uint16_t* __restrict__ Ap = wz + AP_OFF;

    const uint16_t* gs[4];
    #pragma unroll
    for (int l = 0; l < 4; ++l) {
        int u = l * 256 + tid;
        int row = u >> 3, ch = u & 7;
        gs[l] = Ap + (size_t)(loc0 + row) * PLEN + (ch ^ (row & 7)) * 8;
    }
    auto stage = [&](int t, int buf) {
        #pragma unroll
        for (int l = 0; l < 4; ++l)
            __builtin_amdgcn_global_load_lds(
                (const uint32_t*)(gs[l] + t * 64),
                (uint32_t*)((uint16_t*)&Asb[buf][0][0] + (size_t)(l * 256 + wv * 64) * 8),
                16, 0, 0);
    };
    auto ldb = [&](int nt, int ks) -> bf16x8 {
        int ntg = nc * 8 + wn * 4 + nt;
        return *(const bf16x8*)(wz + ((size_t)((ntg * KSTEPS + ks) * 64 + lane)) * 8);
    };

    f32x4 acc[4][4];
    #pragma unroll
    for (int nt = 0; nt < 4; ++nt) {
        float bz = offb[n0 + wn * 64 + nt * 16 + lr];
        f32x4 z = {bz, bz, bz, bz};
        #pragma unroll
        for (int mi = 0; mi < 4; ++mi) acc[mi][nt] = z;
    }

    bf16x8 beA[4], boA[4], beB[4], boB[4];
    stage(0, 0);
    #pragma unroll
    for (int nt = 0; nt < 4; ++nt) { beA[nt] = ldb(nt, 0); boA[nt] = ldb(nt, 1); }
    __syncthreads();

    #pragma unroll 1
    for (int tt = 0; tt < 6; ++tt) {
        const int t0 = tt * 2;
        // iteration t0 (buffer 0): consume set A, prefetch set B for t0+1
        stage(t0 + 1, 1);
        #pragma unroll
        for (int nt = 0; nt < 4; ++nt) { beB[nt] = ldb(nt, 2*t0 + 2); boB[nt] = ldb(nt, 2*t0 + 3); }
        GEMM_ITER(0, beA, boA)
        __syncthreads();
        // iteration t0+1 (buffer 1): consume set B, prefetch set A for t0+2
        if (tt < 5) {
            stage(t0 + 2, 0);
            #pragma unroll
            for (int nt = 0; nt < 4; ++nt) { beA[nt] = ldb(nt, 2*t0 + 4); boA[nt] = ldb(nt, 2*t0 + 5); }
        }
        GEMM_ITER(1, beB, boB)
        __syncthreads();
    }

    #pragma unroll
    for (int nt = 0; nt < 4; ++nt)
      #pragma unroll
      for (int mi = 0; mi < 4; ++mi)
        #pragma unroll
        for (int r = 0; r < 4; ++r) {
            float v  = acc[mi][nt][r];
            float pv = __shfl_xor(v, 1);
            if ((lane & 1) == 0) {
                int row = loc0 + wm * 64 + mi * 16 + lg * 4 + r;
                int q   = (n0 >> 1) + wn * 32 + nt * 8 + (lr >> 1);
                ((uint32_t*)(sa + (size_t)row * PLEN))[q] = pk2(v, pv);
            }
        }
}

// ===== K2: bilinear gather — batched-MLP version (R17, proven) =============
__global__ __launch_bounds__(256)
void k2_gather(const uint16_t* __restrict__ wz, uint16_t* __restrict__ sa) {
    const int tid  = threadIdx.x;
    const int wv   = tid >> 6;            // 0..3
    const int lane = tid & 63;
    int bid = (int)blockIdx.x;
    const int tile = (bid & 7) * 288 + (bid >> 3);   // 2304 = 8 x 288
    const int loc0 = tile * 16;
    const int bimg = loc0 / NPATCH;
    const int p0   = loc0 - bimg * NPATCH;
    const uint16_t* __restrict__ apim = wz + AP_OFF + (size_t)bimg * NPATCH * PLEN;
    const uint32_t HI = 0xFFFF0000u;

    #pragma unroll
    for (int li = 0; li < 4; ++li) {
        const int L   = wv * 4 + li;      // 0..15
        const int p   = p0 + L;
        const int ho  = p / 24;
        const int wo  = p - ho * 24;
        const int by  = ho * 16;
        const int bx  = wo * 16;
        uint16_t* row = sa + (size_t)(loc0 + L) * PLEN;
        const uint32_t* rowu = (const uint32_t*)row;
        uint32_t od0 = rowu[       lane];
        uint32_t od1 = rowu[ 64 +  lane];
        uint32_t od2 = rowu[128 +  lane];
        uint32_t od3 = rowu[192 +  lane];
        asm volatile("s_waitcnt vmcnt(0)" ::: "memory");   // loads before aliasing stores

        uint32_t lov[4][4], hiv[4][4];
        float    wgt[4][4];
        int      par[4][4];

        // ---- Phase A: addresses + weights, issue all 32 load-pairs --------
        #pragma unroll
        for (int s4 = 0; s4 < 4; ++s4) {
            const int q  = s4 * 64 + lane;
            const int qi = q >> 4;
            const int qj = q & 15;
            uint32_t od = (s4 == 0) ? od0 : (s4 == 1) ? od1 : (s4 == 2) ? od2 : od3;
            float dy = bf2f((uint16_t)od);
            float dx = bf2f((uint16_t)(od >> 16));
            float py = (float)(by + qi) + dy;
            float px = (float)(bx + qj) + dx;
            float y0f = floorf(py), x0f = floorf(px);
            float wy1 = py - y0f, wy0 = 1.f - wy1;
            float wx1 = px - x0f, wx0 = 1.f - wx1;
            int y0 = (int)y0f, x0 = (int)x0f;
            #pragma unroll
            for (int c = 0; c < 4; ++c) {
                const int cy = c >> 1, cx = c & 1;
                int yy = y0 + cy, xx = x0 + cx;
                bool valid = ((unsigned)yy < (unsigned)HH) && ((unsigned)xx < (unsigned)WW);
                float w = (cy ? wy1 : wy0) * (cx ? wx1 : wx0);
                wgt[s4][c] = valid ? w : 0.f;
                int yc = min(max(yy, 0), HH - 1);
                int xc = min(max(xx, 0), WW - 1);
                int pp   = (yc >> 4) * 24 + (xc >> 4);
                int elem = ((((yc & 15) << 4) | (xc & 15))) * 3;
                const uint32_t* rp = (const uint32_t*)(apim + (size_t)pp * PLEN);
                lov[s4][c] = rp[elem >> 1];
                hiv[s4][c] = rp[(elem >> 1) + 1];
                par[s4][c] = elem & 1;
            }
        }

        // ---- Phase B: unpack + accumulate + store -------------------------
        #pragma unroll
        for (int s4 = 0; s4 < 4; ++s4) {
            const int q = s4 * 64 + lane;
            float s0 = 0.f, s1 = 0.f, s2 = 0.f;
            #pragma unroll
            for (int c = 0; c < 4; ++c) {
                uint32_t lo32 = lov[s4][c];
                uint32_t hi32 = hiv[s4][c];
                bool odd = par[s4][c] != 0;
                uint32_t pair01 = odd ? ((lo32 >> 16) | (hi32 << 16)) : lo32;
                uint32_t c2b    = odd ? (hi32 & HI) : (hi32 << 16);
                float w = wgt[s4][c];
                s0 += w * bits_f(pair01 << 16);
                s1 += w * bits_f(pair01 & HI);
                s2 += w * bits_f(c2b);
            }
            row[      q] = f2bf(s0);
            row[256 + q] = f2bf(s1);
            row[512 + q] = f2bf(s2);
        }
    }
}

// ===== K3: projection GEMM — deep B-prefetch (full-iteration ahead) ========
__global__ __launch_bounds__(256, 3)
void k3_proj(const uint16_t* __restrict__ wz, const float* __restrict__ projb,
             float* __restrict__ out) {
    __shared__ __align__(16) uint16_t Asb[2][128][64];   // 32 KB dbuf
    const int tid = threadIdx.x, wv = tid >> 6, lane = tid & 63;
    const int lr = lane & 15, lg = lane >> 4;
    const int wm = wv >> 1, wn = wv & 1;
    int bid = (int)blockIdx.x;                  // 1728 = 8 x 216
    const int fin   = (bid & 7) * 216 + (bid >> 3);
    const int mtile = fin / 6;
    const int ncol  = fin - mtile * 6;
    const int loc0  = mtile * 128;
    const int n0    = ncol * 128;
    const uint16_t* __restrict__ sa = wz + SA_OFF;

    const uint16_t* gs[4];
    #pragma unroll
    for (int l = 0; l < 4; ++l) {
        int u = l * 256 + tid;
        int row = u >> 3, ch = u & 7;
        gs[l] = sa + (size_t)(loc0 + row) * PLEN + (ch ^ (row & 7)) * 8;
    }
    auto stage = [&](int t, int buf) {
        #pragma unroll
        for (int l = 0; l < 4; ++l)
            __builtin_amdgcn_global_load_lds(
                (const uint32_t*)(gs[l] + t * 64),
                (uint32_t*)((uint16_t*)&Asb[buf][0][0] + (size_t)(l * 256 + wv * 64) * 8),
                16, 0, 0);
    };
    auto ldb = [&](int nt, int ks) -> bf16x8 {
        int ntg = ncol * 8 + wn * 4 + nt;
        return *(const bf16x8*)(wz + W2_OFF + ((size_t)((ntg * KSTEPS + ks) * 64 + lane)) * 8);
    };

    f32x4 acc[4][4];
    #pragma unroll
    for (int nt = 0; nt < 4; ++nt) {
        float bz = projb[n0 + wn * 64 + nt * 16 + lr];
        f32x4 z = {bz, bz, bz, bz};
        #pragma unroll
        for (int mi = 0; mi < 4; ++mi) acc[mi][nt] = z;
    }

    bf16x8 beA[4], boA[4], beB[4], boB[4];
    stage(0, 0);
    #pragma unroll
    for (int nt = 0; nt < 4; ++nt) { beA[nt] = ldb(nt, 0); boA[nt] = ldb(nt, 1); }
    __syncthreads();

    #pragma unroll 1
    for (int tt = 0; tt < 6; ++tt) {
        const int t0 = tt * 2;
        stage(t0 + 1, 1);
        #pragma unroll
        for (int nt = 0; nt < 4; ++nt) { beB[nt] = ldb(nt, 2*t0 + 2); boB[nt] = ldb(nt, 2*t0 + 3); }
        GEMM_ITER(0, beA, boA)
        __syncthreads();
        if (tt < 5) {
            stage(t0 + 2, 0);
            #pragma unroll
            for (int nt = 0; nt < 4; ++nt) { beA[nt] = ldb(nt, 2*t0 + 4); boA[nt] = ldb(nt, 2*t0 + 5); }
        }
        GEMM_ITER(1, beB, boB)
        __syncthreads();
    }

    #pragma unroll
    for (int mi = 0; mi < 4; ++mi)
      #pragma unroll
      for (int r = 0; r < 4; ++r) {
        int rowg = loc0 + wm * 64 + mi * 16 + lg * 4 + r;
        float* op = out + (size_t)rowg * EMB + n0 + wn * 64;
        #pragma unroll
        for (int nt = 0; nt < 4; ++nt)
            op[nt * 16 + lr] = acc[mi][nt][r];
      }
}

// ===== fallback (tiny ws) ==================================================
__global__ __launch_bounds__(256)
void fallback_kernel(const float* __restrict__ pix, const float* __restrict__ offw,
                     const float* __restrict__ offb, const float* __restrict__ projw,
                     const float* __restrict__ projb, float* __restrict__ out) {
    __shared__ float buf[8][PLEN];
    const int tid = threadIdx.x;
    const int loc0 = blockIdx.x * 8;
    #pragma unroll
    for (int r = 0; r < 6; ++r) {
        int item = tid + r * 256;
        int l = item / 192, k = (item - l * 192) * 4;
        int c = k >> 8, i = (k >> 4) & 15, j = k & 15;
        int flat = loc0 + l, b = flat / NPATCH, p = flat - b * NPATCH;
        int ho = p / 24, wo = p - ho * 24;
        *(float4*)(&buf[l][k]) = *(const float4*)(pix +
            (((size_t)b * NC + c) * HH + (size_t)ho * 16 + i) * WW + wo * 16 + j);
    }
    __syncthreads();
    float dy[8], dx[8];
    {
        float a0[8], a1[8];
        float b0 = offb[2 * tid], b1 = offb[2 * tid + 1];
        #pragma unroll
        for (int l = 0; l < 8; ++l) { a0[l] = b0; a1[l] = b1; }
        const float4* w0 = (const float4*)(offw + (size_t)(2 * tid) * PLEN);
        const float4* w1 = w0 + PLEN / 4;
        for (int k4 = 0; k4 < PLEN / 4; ++k4) {
            float4 wa = w0[k4], wb = w1[k4];
            #pragma unroll
            for (int l = 0; l < 8; ++l) {
                float4 pv = *(const float4*)(&buf[l][k4 * 4]);
                a0[l] += wa.x*pv.x + wa.y*pv.y + wa.z*pv.z + wa.w*pv.w;
                a1[l] += wb.x*pv.x + wb.y*pv.y + wb.z*pv.z + wb.w*pv.w;
            }
        }
        #pragma unroll
        for (int l = 0; l < 8; ++l) { dy[l] = a0[l]; dx[l] = a1[l]; }
    }
    __syncthreads();
    {
        const int i = tid >> 4, j = tid & 15;
        #pragma unroll
        for (int l = 0; l < 8; ++l) {
            int flat = loc0 + l, b = flat / NPATCH, p = flat - b * NPATCH;
            int ho = p / 24, wo = p - ho * 24;
            float py = (float)(ho * 16 + i) + dy[l];
            float px = (float)(wo * 16 + j) + dx[l];
            float y0 = floorf(py), x0 = floorf(px);
            float wy1 = py - y0, wy0 = 1.f - wy1, wx1 = px - x0, wx0 = 1.f - wx1;
            const float* pb = pix + (size_t)b * NC * NPIX;
            float s0 = 0, s1 = 0, s2 = 0;
            #pragma unroll
            for (int cy = 0; cy < 2; ++cy)
              #pragma unroll
              for (int cx = 0; cx < 2; ++cx) {
                int yy = (int)y0 + cy, xx = (int)x0 + cx;
                float w = (cy ? wy1 : wy0) * (cx ? wx1 : wx0);
                if ((unsigned)yy < (unsigned)HH && (unsigned)xx < (unsigned)WW) {
                    int idx = yy * WW + xx;
                    s0 += w * pb[idx]; s1 += w * pb[NPIX + idx]; s2 += w * pb[2*NPIX + idx];
                }
              }
            buf[l][tid] = s0; buf[l][256 + tid] = s1; buf[l][512 + tid] = s2;
        }
    }
    __syncthreads();
    {
        float aA[8], aB[8], aC[8];
        float bA = projb[tid], bB = projb[tid + 256], bC = projb[tid + 512];
        #pragma unroll
        for (int l = 0; l < 8; ++l) { aA[l] = bA; aB[l] = bB; aC[l] = bC; }
        const float4* wA = (const float4*)(projw + (size_t)tid * PLEN);
        const float4* wB = (const float4*)(projw + (size_t)(tid + 256) * PLEN);
        const float4* wC = (const float4*)(projw + (size_t)(tid + 512) * PLEN);
        for (int k4 = 0; k4 < PLEN / 4; ++k4) {
            float4 a = wA[k4], bq = wB[k4], cq = wC[k4];
            #pragma unroll
            for (int l = 0; l < 8; ++l) {
                float4 pv = *(const float4*)(&buf[l][k4 * 4]);
                aA[l] += a.x*pv.x + a.y*pv.y + a.z*pv.z + a.w*pv.w;
                aB[l] += bq.x*pv.x + bq.y*pv.y + bq.z*pv.z + bq.w*pv.w;
                aC[l] += cq.x*pv.x + cq.y*pv.y + cq.z*pv.z + cq.w*pv.w;
            }
        }
        #pragma unroll
        for (int l = 0; l < 8; ++l) {
            float* op = out + (size_t)(loc0 + l) * EMB;
            op[tid] = aA[l]; op[tid + 256] = aB[l]; op[tid + 512] = aC[l];
        }
    }
}

extern "C" void kernel_launch(void* const* d_in, const int* in_sizes, int n_in,
                              void* d_out, int out_size, void* d_ws, size_t ws_size,
                              hipStream_t stream) {
    const float* pix   = (const float*)d_in[0];
    const float* offw  = (const float*)d_in[1];
    const float* offb  = (const float*)d_in[2];
    const float* projw = (const float*)d_in[3];
    const float* projb = (const float*)d_in[4];
    float* out = (float*)d_out;
    uint16_t* wz = (uint16_t*)d_ws;

    const size_t ws_needed = ((size_t)SA_OFF + (size_t)NLOC * PLEN) * 2;  // ~115.2 MB

    if (ws_size >= ws_needed) {
        uint16_t* sa = wz + SA_OFF;
        p0_prepass<<<P0_WBLKS + P0_BANDS, 256, 0, stream>>>(offw, projw, pix, wz);
        k1_offgemm<<<1152, 256, 0, stream>>>(wz, offb, sa);
        k2_gather<<<2304, 256, 0, stream>>>(wz, sa);
        k3_proj<<<1728, 256, 0, stream>>>(wz, projb, out);
    } else {
        fallback_kernel<<<NLOC / 8, 256, 0, stream>>>(pix, offw, offb, projw, projb, out);
    }
}

// Round 19
// 172.603 us; speedup vs baseline: 1.0437x; 1.0437x over previous
//
#include <hip/hip_runtime.h>
#include <stdint.h>

typedef __bf16 bf16x8 __attribute__((ext_vector_type(8)));
typedef float  f32x4  __attribute__((ext_vector_type(4)));

#define HH 384
#define WW 384
#define NPIX (HH*WW)
#define NC 3
#define NPATCH 576
#define EMB 768
#define PLEN 768
#define KSTEPS 24
#define NLOC (64*576)            /* 36864 */
#define W1_UNITS (32*KSTEPS*64)  /* 49152 16B-units */
#define W2_UNITS (48*KSTEPS*64)  /* 73728 16B-units */
#define W2_OFF   (W1_UNITS*8)                 /* u16 units */
#define AP_OFF   ((W1_UNITS+W2_UNITS)*8)      /* u16 units */
#define SA_OFF   (AP_OFF + NLOC*PLEN)         /* u16 units */
#define P0_WBLKS ((W1_UNITS+W2_UNITS)/256)    /* 480 */
#define P0_BANDS (64*24)                      /* 1536 */

__device__ __forceinline__ uint16_t f2bf(float f) {
    uint32_t u = __builtin_bit_cast(uint32_t, f);
    u += 0x7FFFu + ((u >> 16) & 1u);
    return (uint16_t)(u >> 16);
}
__device__ __forceinline__ uint32_t pk2(float a, float b) {
    return (uint32_t)f2bf(a) | ((uint32_t)f2bf(b) << 16);
}
__device__ __forceinline__ float bf2f(uint16_t u) {
    return __builtin_bit_cast(float, (uint32_t)u << 16);
}
__device__ __forceinline__ float bits_f(uint32_t u) {
    return __builtin_bit_cast(float, u);
}

// ===== P0 ==================================================================
// Weights -> MFMA-fragment bf16. W1 uses the PERMUTED k-order (k = q*3+c,
// matching the interleaved Ap): src elem = (k%3)*256 + k/3. W2 stays planar.
// Band blocks: im2col with channel-interleaved rows: Ap[patch][q*3+c].
__global__ __launch_bounds__(256)
void p0_prepass(const float* __restrict__ offw, const float* __restrict__ projw,
                const float* __restrict__ pix, uint16_t* __restrict__ wz) {
    __shared__ uint16_t L[3 * 16 * 384];   // planar band cache (bf16)
    int b = blockIdx.x;
    if (b < P0_WBLKS) {
        int u = b * 256 + threadIdx.x;
        int lane = u & 63;
        if (u < W1_UNITS) {
            int t  = u >> 6;
            int ks = t % KSTEPS;
            int nt = t / KSTEPS;
            int n  = nt * 16 + (lane & 15);
            int k0 = ks * 32 + (lane >> 4) * 8;
            const float* src = offw + (size_t)n * PLEN;
            uint16_t tmp[8];
            #pragma unroll
            for (int e = 0; e < 8; ++e) {
                int k = k0 + e;
                int q = k / 3, c = k - q * 3;
                tmp[e] = f2bf(src[c * 256 + q]);
            }
            uint4 w;
            w.x = tmp[0] | ((uint32_t)tmp[1] << 16);
            w.y = tmp[2] | ((uint32_t)tmp[3] << 16);
            w.z = tmp[4] | ((uint32_t)tmp[5] << 16);
            w.w = tmp[6] | ((uint32_t)tmp[7] << 16);
            *(uint4*)(wz + (size_t)u * 8) = w;
        } else {
            int uu = u - W1_UNITS;
            int t2 = uu >> 6;
            int ks = t2 % KSTEPS;
            int nt = t2 / KSTEPS;
            int n  = nt * 16 + (lane & 15);
            int k0 = ks * 32 + (lane >> 4) * 8;
            const float4* s4 = (const float4*)(projw + (size_t)n * PLEN + k0);
            float4 v0 = s4[0], v1 = s4[1];
            uint4 w;
            w.x = pk2(v0.x, v0.y); w.y = pk2(v0.z, v0.w);
            w.z = pk2(v1.x, v1.y); w.w = pk2(v1.z, v1.w);
            *(uint4*)(wz + (size_t)u * 8) = w;
        }
        return;
    }
    int band = b - P0_WBLKS;               // 0..1535
    int img  = band / 24;
    int yb   = band - img * 24;            // ho
    const float* src = pix + (size_t)img * NC * NPIX + (size_t)yb * 16 * WW;
    #pragma unroll
    for (int i = 0; i < 18; ++i) {
        int u = threadIdx.x + i * 256;     // 0..4607 float4 groups
        int c = u / 1536;
        int r = u - c * 1536;
        float4 v = *(const float4*)(src + (size_t)c * NPIX + (size_t)r * 4);
        uint2 o;
        o.x = pk2(v.x, v.y);
        o.y = pk2(v.z, v.w);
        *(uint2*)&L[c * 6144 + r * 4] = o;
    }
    __syncthreads();
    // emit 24 patch rows, interleaved k = q*3+c, contiguous 1536B each
    uint16_t* ap = wz + AP_OFF + (size_t)(img * NPATCH + yb * 24) * PLEN;
    #pragma unroll
    for (int i = 0; i < 9; ++i) {
        int u  = threadIdx.x + i * 256;    // 0..2303 chunks of 8
        int p  = u / 96;
        int k8 = (u - p * 96) * 8;
        uint16_t tmp[8];
        #pragma unroll
        for (int e = 0; e < 8; ++e) {
            int k = k8 + e;
            int q = k / 3, c = k - q * 3;
            int ii = q >> 4, j = q & 15;
            tmp[e] = L[(c * 16 + ii) * 384 + p * 16 + j];
        }
        uint4 d;
        d.x = tmp[0] | ((uint32_t)tmp[1] << 16);
        d.y = tmp[2] | ((uint32_t)tmp[3] << 16);
        d.z = tmp[4] | ((uint32_t)tmp[5] << 16);
        d.w = tmp[6] | ((uint32_t)tmp[7] << 16);
        *(uint4*)(ap + (size_t)p * PLEN + k8) = d;
    }
}

// ===== K1: GEMM1 (offset conv) — A via global_load_lds (pre-swizzled) ======
__global__ __launch_bounds__(256, 3)
void k1_offgemm(const uint16_t* __restrict__ wz, const float* __restrict__ offb,
                uint16_t* __restrict__ sa) {
    __shared__ __align__(16) uint16_t Asb[2][128][64];   // 32 KB dbuf
    const int tid = threadIdx.x, wv = tid >> 6, lane = tid & 63;
    const int lr = lane & 15, lg = lane >> 4;
    const int wm = wv >> 1, wn = wv & 1;
    int bid = (int)blockIdx.x;                 // 1152 = 8 x 144
    const int fin   = (bid & 7) * 144 + (bid >> 3);
    const int mtile = fin >> 2;
    const int nc    = fin & 3;
    const int loc0  = mtile * 128;
    const int n0    = nc * 128;
    const uint16_t* __restrict__ Ap = wz + AP_OFF;

    const uint16_t* gs[4];
    #pragma unroll
    for (int l = 0; l < 4; ++l) {
        int u = l * 256 + tid;
        int row = u >> 3, ch = u & 7;
        gs[l] = Ap + (size_t)(loc0 + row) * PLEN + (ch ^ (row & 7)) * 8;
    }
    auto stage = [&](int t, int buf) {
        #pragma unroll
        for (int l = 0; l < 4; ++l)
            __builtin_amdgcn_global_load_lds(
                (const uint32_t*)(gs[l] + t * 64),
                (uint32_t*)((uint16_t*)&Asb[buf][0][0] + (size_t)(l * 256 + wv * 64) * 8),
                16, 0, 0);
    };
    auto ldb = [&](int nt, int ks) -> bf16x8 {
        int ntg = nc * 8 + wn * 4 + nt;
        return *(const bf16x8*)(wz + ((size_t)((ntg * KSTEPS + ks) * 64 + lane)) * 8);
    };

    f32x4 acc[4][4];
    #pragma unroll
    for (int nt = 0; nt < 4; ++nt) {
        float bz = offb[n0 + wn * 64 + nt * 16 + lr];
        f32x4 z = {bz, bz, bz, bz};
        #pragma unroll
        for (int mi = 0; mi < 4; ++mi) acc[mi][nt] = z;
    }

    bf16x8 ba[4], bb[4];
    stage(0, 0);
    #pragma unroll
    for (int nt = 0; nt < 4; ++nt) ba[nt] = ldb(nt, 0);
    __syncthreads();

    #pragma unroll 1
    for (int t = 0; t < 12; ++t) {
        const int cur = t & 1;
        if (t < 11) stage(t + 1, cur ^ 1);
        {
            #pragma unroll
            for (int nt = 0; nt < 4; ++nt) bb[nt] = ldb(nt, 2 * t + 1);
            const int u0 = (lg ^ (lr & 7)) * 8;
            bf16x8 a0 = *(const bf16x8*)&Asb[cur][wm * 64 +  0 + lr][u0];
            bf16x8 a1 = *(const bf16x8*)&Asb[cur][wm * 64 + 16 + lr][u0];
            bf16x8 a2 = *(const bf16x8*)&Asb[cur][wm * 64 + 32 + lr][u0];
            bf16x8 a3 = *(const bf16x8*)&Asb[cur][wm * 64 + 48 + lr][u0];
            #pragma unroll
            for (int nt = 0; nt < 4; ++nt) {
                acc[0][nt] = __builtin_amdgcn_mfma_f32_16x16x32_bf16(a0, ba[nt], acc[0][nt], 0, 0, 0);
                acc[1][nt] = __builtin_amdgcn_mfma_f32_16x16x32_bf16(a1, ba[nt], acc[1][nt], 0, 0, 0);
                acc[2][nt] = __builtin_amdgcn_mfma_f32_16x16x32_bf16(a2, ba[nt], acc[2][nt], 0, 0, 0);
                acc[3][nt] = __builtin_amdgcn_mfma_f32_16x16x32_bf16(a3, ba[nt], acc[3][nt], 0, 0, 0);
            }
        }
        {
            if (t < 11) {
                #pragma unroll
                for (int nt = 0; nt < 4; ++nt) ba[nt] = ldb(nt, 2 * t + 2);
            }
            const int u1 = ((4 + lg) ^ (lr & 7)) * 8;
            bf16x8 a0 = *(const bf16x8*)&Asb[cur][wm * 64 +  0 + lr][u1];
            bf16x8 a1 = *(const bf16x8*)&Asb[cur][wm * 64 + 16 + lr][u1];
            bf16x8 a2 = *(const bf16x8*)&Asb[cur][wm * 64 + 32 + lr][u1];
            bf16x8 a3 = *(const bf16x8*)&Asb[cur][wm * 64 + 48 + lr][u1];
            #pragma unroll
            for (int nt = 0; nt < 4; ++nt) {
                acc[0][nt] = __builtin_amdgcn_mfma_f32_16x16x32_bf16(a0, bb[nt], acc[0][nt], 0, 0, 0);
                acc[1][nt] = __builtin_amdgcn_mfma_f32_16x16x32_bf16(a1, bb[nt], acc[1][nt], 0, 0, 0);
                acc[2][nt] = __builtin_amdgcn_mfma_f32_16x16x32_bf16(a2, bb[nt], acc[2][nt], 0, 0, 0);
                acc[3][nt] = __builtin_amdgcn_mfma_f32_16x16x32_bf16(a3, bb[nt], acc[3][nt], 0, 0, 0);
            }
        }
        __syncthreads();
    }

    #pragma unroll
    for (int nt = 0; nt < 4; ++nt)
      #pragma unroll
      for (int mi = 0; mi < 4; ++mi)
        #pragma unroll
        for (int r = 0; r < 4; ++r) {
            float v  = acc[mi][nt][r];
            float pv = __shfl_xor(v, 1);
            if ((lane & 1) == 0) {
                int row = loc0 + wm * 64 + mi * 16 + lg * 4 + r;
                int q   = (n0 >> 1) + wn * 32 + nt * 8 + (lr >> 1);
                ((uint32_t*)(sa + (size_t)row * PLEN))[q] = pk2(v, pv);
            }
        }
}

// ===== K2: bilinear gather — batched-MLP version ===========================
// Phase A issues ALL 32 corner dword-pairs for the patch's 4 samples into
// registers (invalid corners clamped in-range with weight=0 — zero-padding
// preserved, no divergence); phase B unpacks + accumulates.
__global__ __launch_bounds__(256)
void k2_gather(const uint16_t* __restrict__ wz, uint16_t* __restrict__ sa) {
    const int tid  = threadIdx.x;
    const int wv   = tid >> 6;            // 0..3
    const int lane = tid & 63;
    int bid = (int)blockIdx.x;
    const int tile = (bid & 7) * 288 + (bid >> 3);   // 2304 = 8 x 288
    const int loc0 = tile * 16;
    const int bimg = loc0 / NPATCH;
    const int p0   = loc0 - bimg * NPATCH;
    const uint16_t* __restrict__ apim = wz + AP_OFF + (size_t)bimg * NPATCH * PLEN;
    const uint32_t HI = 0xFFFF0000u;

    #pragma unroll
    for (int li = 0; li < 4; ++li) {
        const int L   = wv * 4 + li;      // 0..15
        const int p   = p0 + L;
        const int ho  = p / 24;
        const int wo  = p - ho * 24;
        const int by  = ho * 16;
        const int bx  = wo * 16;
        uint16_t* row = sa + (size_t)(loc0 + L) * PLEN;
        const uint32_t* rowu = (const uint32_t*)row;
        uint32_t od0 = rowu[       lane];
        uint32_t od1 = rowu[ 64 +  lane];
        uint32_t od2 = rowu[128 +  lane];
        uint32_t od3 = rowu[192 +  lane];
        asm volatile("s_waitcnt vmcnt(0)" ::: "memory");   // loads before aliasing stores

        uint32_t lov[4][4], hiv[4][4];
        float    wgt[4][4];
        int      par[4][4];

        // ---- Phase A: addresses + weights, issue all 32 load-pairs --------
        #pragma unroll
        for (int s4 = 0; s4 < 4; ++s4) {
            const int q  = s4 * 64 + lane;
            const int qi = q >> 4;
            const int qj = q & 15;
            uint32_t od = (s4 == 0) ? od0 : (s4 == 1) ? od1 : (s4 == 2) ? od2 : od3;
            float dy = bf2f((uint16_t)od);
            float dx = bf2f((uint16_t)(od >> 16));
            float py = (float)(by + qi) + dy;
            float px = (float)(bx + qj) + dx;
            float y0f = floorf(py), x0f = floorf(px);
            float wy1 = py - y0f, wy0 = 1.f - wy1;
            float wx1 = px - x0f, wx0 = 1.f - wx1;
            int y0 = (int)y0f, x0 = (int)x0f;
            #pragma unroll
            for (int c = 0; c < 4; ++c) {
                const int cy = c >> 1, cx = c & 1;
                int yy = y0 + cy, xx = x0 + cx;
                bool valid = ((unsigned)yy < (unsigned)HH) && ((unsigned)xx < (unsigned)WW);
                float w = (cy ? wy1 : wy0) * (cx ? wx1 : wx0);
                wgt[s4][c] = valid ? w : 0.f;
                int yc = min(max(yy, 0), HH - 1);
                int xc = min(max(xx, 0), WW - 1);
                int pp   = (yc >> 4) * 24 + (xc >> 4);
                int elem = ((((yc & 15) << 4) | (xc & 15))) * 3;
                const uint32_t* rp = (const uint32_t*)(apim + (size_t)pp * PLEN);
                lov[s4][c] = rp[elem >> 1];
                hiv[s4][c] = rp[(elem >> 1) + 1];
                par[s4][c] = elem & 1;
            }
        }

        // ---- Phase B: unpack + accumulate + store -------------------------
        #pragma unroll
        for (int s4 = 0; s4 < 4; ++s4) {
            const int q = s4 * 64 + lane;
            float s0 = 0.f, s1 = 0.f, s2 = 0.f;
            #pragma unroll
            for (int c = 0; c < 4; ++c) {
                uint32_t lo32 = lov[s4][c];
                uint32_t hi32 = hiv[s4][c];
                bool odd = par[s4][c] != 0;
                uint32_t pair01 = odd ? ((lo32 >> 16) | (hi32 << 16)) : lo32;
                uint32_t c2b    = odd ? (hi32 & HI) : (hi32 << 16);
                float w = wgt[s4][c];
                s0 += w * bits_f(pair01 << 16);
                s1 += w * bits_f(pair01 & HI);
                s2 += w * bits_f(c2b);
            }
            row[      q] = f2bf(s0);
            row[256 + q] = f2bf(s1);
            row[512 + q] = f2bf(s2);
        }
    }
}

// ===== K3: projection GEMM — A via global_load_lds (pre-swizzled) ==========
__global__ __launch_bounds__(256, 3)
void k3_proj(const uint16_t* __restrict__ wz, const float* __restrict__ projb,
             float* __restrict__ out) {
    __shared__ __align__(16) uint16_t Asb[2][128][64];   // 32 KB dbuf
    const int tid = threadIdx.x, wv = tid >> 6, lane = tid & 63;
    const int lr = lane & 15, lg = lane >> 4;
    const int wm = wv >> 1, wn = wv & 1;
    int bid = (int)blockIdx.x;                  // 1728 = 8 x 216
    const int fin   = (bid & 7) * 216 + (bid >> 3);
    const int mtile = fin / 6;
    const int ncol  = fin - mtile * 6;
    const int loc0  = mtile * 128;
    const int n0    = ncol * 128;
    const uint16_t* __restrict__ sa = wz + SA_OFF;

    const uint16_t* gs[4];
    #pragma unroll
    for (int l = 0; l < 4; ++l) {
        int u = l * 256 + tid;
        int row = u >> 3, ch = u & 7;
        gs[l] = sa + (size_t)(loc0 + row) * PLEN + (ch ^ (row & 7)) * 8;
    }
    auto stage = [&](int t, int buf) {
        #pragma unroll
        for (int l = 0; l < 4; ++l)
            __builtin_amdgcn_global_load_lds(
                (const uint32_t*)(gs[l] + t * 64),
                (uint32_t*)((uint16_t*)&Asb[buf][0][0] + (size_t)(l * 256 + wv * 64) * 8),
                16, 0, 0);
    };
    auto ldb = [&](int nt, int ks) -> bf16x8 {
        int ntg = ncol * 8 + wn * 4 + nt;
        return *(const bf16x8*)(wz + W2_OFF + ((size_t)((ntg * KSTEPS + ks) * 64 + lane)) * 8);
    };

    f32x4 acc[4][4];
    #pragma unroll
    for (int nt = 0; nt < 4; ++nt) {
        float bz = projb[n0 + wn * 64 + nt * 16 + lr];
        f32x4 z = {bz, bz, bz, bz};
        #pragma unroll
        for (int mi = 0; mi < 4; ++mi) acc[mi][nt] = z;
    }

    bf16x8 ba[4], bb[4];
    stage(0, 0);
    #pragma unroll
    for (int nt = 0; nt < 4; ++nt) ba[nt] = ldb(nt, 0);
    __syncthreads();

    #pragma unroll 1
    for (int t = 0; t < 12; ++t) {
        const int cur = t & 1;
        if (t < 11) stage(t + 1, cur ^ 1);
        {
            #pragma unroll
            for (int nt = 0; nt < 4; ++nt) bb[nt] = ldb(nt, 2 * t + 1);
            const int u0 = (lg ^ (lr & 7)) * 8;
            bf16x8 a0 = *(const bf16x8*)&Asb[cur][wm * 64 +  0 + lr][u0];
            bf16x8 a1 = *(const bf16x8*)&Asb[cur][wm * 64 + 16 + lr][u0];
            bf16x8 a2 = *(const bf16x8*)&Asb[cur][wm * 64 + 32 + lr][u0];
            bf16x8 a3 = *(const bf16x8*)&Asb[cur][wm * 64 + 48 + lr][u0];
            #pragma unroll
            for (int nt = 0; nt < 4; ++nt) {
                acc[0][nt] = __builtin_amdgcn_mfma_f32_16x16x32_bf16(a0, ba[nt], acc[0][nt], 0, 0, 0);
                acc[1][nt] = __builtin_amdgcn_mfma_f32_16x16x32_bf16(a1, ba[nt], acc[1][nt], 0, 0, 0);
                acc[2][nt] = __builtin_amdgcn_mfma_f32_16x16x32_bf16(a2, ba[nt], acc[2][nt], 0, 0, 0);
                acc[3][nt] = __builtin_amdgcn_mfma_f32_16x16x32_bf16(a3, ba[nt], acc[3][nt], 0, 0, 0);
            }
        }
        {
            if (t < 11) {
                #pragma unroll
                for (int nt = 0; nt < 4; ++nt) ba[nt] = ldb(nt, 2 * t + 2);
            }
            const int u1 = ((4 + lg) ^ (lr & 7)) * 8;
            bf16x8 a0 = *(const bf16x8*)&Asb[cur][wm * 64 +  0 + lr][u1];
            bf16x8 a1 = *(const bf16x8*)&Asb[cur][wm * 64 + 16 + lr][u1];
            bf16x8 a2 = *(const bf16x8*)&Asb[cur][wm * 64 + 32 + lr][u1];
            bf16x8 a3 = *(const bf16x8*)&Asb[cur][wm * 64 + 48 + lr][u1];
            #pragma unroll
            for (int nt = 0; nt < 4; ++nt) {
                acc[0][nt] = __builtin_amdgcn_mfma_f32_16x16x32_bf16(a0, bb[nt], acc[0][nt], 0, 0, 0);
                acc[1][nt] = __builtin_amdgcn_mfma_f32_16x16x32_bf16(a1, bb[nt], acc[1][nt], 0, 0, 0);
                acc[2][nt] = __builtin_amdgcn_mfma_f32_16x16x32_bf16(a2, bb[nt], acc[2][nt], 0, 0, 0);
                acc[3][nt] = __builtin_amdgcn_mfma_f32_16x16x32_bf16(a3, bb[nt], acc[3][nt], 0, 0, 0);
            }
        }
        __syncthreads();
    }

    #pragma unroll
    for (int mi = 0; mi < 4; ++mi)
      #pragma unroll
      for (int r = 0; r < 4; ++r) {
        int rowg = loc0 + wm * 64 + mi * 16 + lg * 4 + r;
        float* op = out + (size_t)rowg * EMB + n0 + wn * 64;
        #pragma unroll
        for (int nt = 0; nt < 4; ++nt)
            op[nt * 16 + lr] = acc[mi][nt][r];
      }
}

// ===== fallback (tiny ws) ==================================================
__global__ __launch_bounds__(256)
void fallback_kernel(const float* __restrict__ pix, const float* __restrict__ offw,
                     const float* __restrict__ offb, const float* __restrict__ projw,
                     const float* __restrict__ projb, float* __restrict__ out) {
    __shared__ float buf[8][PLEN];
    const int tid = threadIdx.x;
    const int loc0 = blockIdx.x * 8;
    #pragma unroll
    for (int r = 0; r < 6; ++r) {
        int item = tid + r * 256;
        int l = item / 192, k = (item - l * 192) * 4;
        int c = k >> 8, i = (k >> 4) & 15, j = k & 15;
        int flat = loc0 + l, b = flat / NPATCH, p = flat - b * NPATCH;
        int ho = p / 24, wo = p - ho * 24;
        *(float4*)(&buf[l][k]) = *(const float4*)(pix +
            (((size_t)b * NC + c) * HH + (size_t)ho * 16 + i) * WW + wo * 16 + j);
    }
    __syncthreads();
    float dy[8], dx[8];
    {
        float a0[8], a1[8];
        float b0 = offb[2 * tid], b1 = offb[2 * tid + 1];
        #pragma unroll
        for (int l = 0; l < 8; ++l) { a0[l] = b0; a1[l] = b1; }
        const float4* w0 = (const float4*)(offw + (size_t)(2 * tid) * PLEN);
        const float4* w1 = w0 + PLEN / 4;
        for (int k4 = 0; k4 < PLEN / 4; ++k4) {
            float4 wa = w0[k4], wb = w1[k4];
            #pragma unroll
            for (int l = 0; l < 8; ++l) {
                float4 pv = *(const float4*)(&buf[l][k4 * 4]);
                a0[l] += wa.x*pv.x + wa.y*pv.y + wa.z*pv.z + wa.w*pv.w;
                a1[l] += wb.x*pv.x + wb.y*pv.y + wb.z*pv.z + wb.w*pv.w;
            }
        }
        #pragma unroll
        for (int l = 0; l < 8; ++l) { dy[l] = a0[l]; dx[l] = a1[l]; }
    }
    __syncthreads();
    {
        const int i = tid >> 4, j = tid & 15;
        #pragma unroll
        for (int l = 0; l < 8; ++l) {
            int flat = loc0 + l, b = flat / NPATCH, p = flat - b * NPATCH;
            int ho = p / 24, wo = p - ho * 24;
            float py = (float)(ho * 16 + i) + dy[l];
            float px = (float)(wo * 16 + j) + dx[l];
            float y0 = floorf(py), x0 = floorf(px);
            float wy1 = py - y0, wy0 = 1.f - wy1, wx1 = px - x0, wx0 = 1.f - wx1;
            const float* pb = pix + (size_t)b * NC * NPIX;
            float s0 = 0, s1 = 0, s2 = 0;
            #pragma unroll
            for (int cy = 0; cy < 2; ++cy)
              #pragma unroll
              for (int cx = 0; cx < 2; ++cx) {
                int yy = (int)y0 + cy, xx = (int)x0 + cx;
                float w = (cy ? wy1 : wy0) * (cx ? wx1 : wx0);
                if ((unsigned)yy < (unsigned)HH && (unsigned)xx < (unsigned)WW) {
                    int idx = yy * WW + xx;
                    s0 += w * pb[idx]; s1 += w * pb[NPIX + idx]; s2 += w * pb[2*NPIX + idx];
                }
              }
            buf[l][tid] = s0; buf[l][256 + tid] = s1; buf[l][512 + tid] = s2;
        }
    }
    __syncthreads();
    {
        float aA[8], aB[8], aC[8];
        float bA = projb[tid], bB = projb[tid + 256], bC = projb[tid + 512];
        #pragma unroll
        for (int l = 0; l < 8; ++l) { aA[l] = bA; aB[l] = bB; aC[l] = bC; }
        const float4* wA = (const float4*)(projw + (size_t)tid * PLEN);
        const float4* wB = (const float4*)(projw + (size_t)(tid + 256) * PLEN);
        const float4* wC = (const float4*)(projw + (size_t)(tid + 512) * PLEN);
        for (int k4 = 0; k4 < PLEN / 4; ++k4) {
            float4 a = wA[k4], bq = wB[k4], cq = wC[k4];
            #pragma unroll
            for (int l = 0; l < 8; ++l) {
                float4 pv = *(const float4*)(&buf[l][k4 * 4]);
                aA[l] += a.x*pv.x + a.y*pv.y + a.z*pv.z + a.w*pv.w;
                aB[l] += bq.x*pv.x + bq.y*pv.y + bq.z*pv.z + bq.w*pv.w;
                aC[l] += cq.x*pv.x + cq.y*pv.y + cq.z*pv.z + cq.w*pv.w;
            }
        }
        #pragma unroll
        for (int l = 0; l < 8; ++l) {
            float* op = out + (size_t)(loc0 + l) * EMB;
            op[tid] = aA[l]; op[tid + 256] = aB[l]; op[tid + 512] = aC[l];
        }
    }
}

extern "C" void kernel_launch(void* const* d_in, const int* in_sizes, int n_in,
                              void* d_out, int out_size, void* d_ws, size_t ws_size,
                              hipStream_t stream) {
    const float* pix   = (const float*)d_in[0];
    const float* offw  = (const float*)d_in[1];
    const float* offb  = (const float*)d_in[2];
    const float* projw = (const float*)d_in[3];
    const float* projb = (const float*)d_in[4];
    float* out = (float*)d_out;
    uint16_t* wz = (uint16_t*)d_ws;

    const size_t ws_needed = ((size_t)SA_OFF + (size_t)NLOC * PLEN) * 2;  // ~115.2 MB

    if (ws_size >= ws_needed) {
        uint16_t* sa = wz + SA_OFF;
        p0_prepass<<<P0_WBLKS + P0_BANDS, 256, 0, stream>>>(offw, projw, pix, wz);
        k1_offgemm<<<1152, 256, 0, stream>>>(wz, offb, sa);
        k2_gather<<<2304, 256, 0, stream>>>(wz, sa);
        k3_proj<<<1728, 256, 0, stream>>>(wz, projb, out);
    } else {
        fallback_kernel<<<NLOC / 8, 256, 0, stream>>>(pix, offw, offb, projw, projb, out);
    }
}